// Round 7
// baseline (262.842 us; speedup 1.0000x reference)
//
#include <hip/hip_runtime.h>

#define TT 28
#define L2E 1.4426950408889634f

typedef __attribute__((ext_vector_type(8))) short bf16x8;
typedef __attribute__((ext_vector_type(4))) float f32x4;
typedef _Float16 h2 __attribute__((ext_vector_type(2)));
typedef __fp16 fp16x2 __attribute__((ext_vector_type(2)));

__device__ __forceinline__ unsigned fbits(float f){ union{float f; unsigned u;} v; v.f=f; return v.u; }
__device__ __forceinline__ float bitsf(unsigned u){ union{unsigned u; float f;} v; v.u=u; return v.f; }
__device__ __forceinline__ short bf16rnd(float f){ return (short)((fbits(f)+0x8000u)>>16); }

__device__ __forceinline__ h2 PKH2(float a, float b){
    fp16x2 t = __builtin_amdgcn_cvt_pkrtz(a, b);   // v_cvt_pkrtz_f16_f32
    return __builtin_bit_cast(h2, t);
}

#if __has_builtin(__builtin_amdgcn_fdot2)
#define FDOT2(a,b,c) __builtin_amdgcn_fdot2((a),(b),(c),false)
#else
__device__ __forceinline__ float FDOT2(h2 a, h2 b, float c){
    return fmaf((float)a.x,(float)b.x, fmaf((float)a.y,(float)b.y,(c)));
}
#endif
#if __has_builtin(__builtin_amdgcn_exp2f)
#define EXP2(x) __builtin_amdgcn_exp2f(x)
#else
#define EXP2(x) exp2f(x)
#endif
#if __has_builtin(__builtin_amdgcn_rcpf)
#define RCP(x) __builtin_amdgcn_rcpf(x)
#else
#define RCP(x) (1.f/(x))
#endif

// quad_perm DPP: xor1 = [1,0,3,2] = 0xB1, xor2 = [2,3,0,1] = 0x4E. Full-rate VALU, no LDS pipe.
#if __has_builtin(__builtin_amdgcn_mov_dpp)
#define DPP_XOR1(x) __builtin_bit_cast(float, __builtin_amdgcn_mov_dpp(__builtin_bit_cast(int,(float)(x)), 0xB1, 0xF, 0xF, true))
#define DPP_XOR2(x) __builtin_bit_cast(float, __builtin_amdgcn_mov_dpp(__builtin_bit_cast(int,(float)(x)), 0x4E, 0xF, 0xF, true))
#else
#define DPP_XOR1(x) __shfl_xor((x), 1, 64)
#define DPP_XOR2(x) __shfl_xor((x), 2, 64)
#endif

// ======================= Kernel A: h0/q producer =======================
// Streams x (128 MB), computes h0 = x@Wp^T+bp and q = relu(x@Wg1^T+bg1)
// via bf16 hi/lo MFMA; writes [131072][16] f32 to d_ws. No LDS, no barrier.
__global__ __launch_bounds__(256) __attribute__((amdgpu_waves_per_eu(5, 8)))
void phaseA_kernel(const float* __restrict__ x,
                   const float* __restrict__ Wp,  const float* __restrict__ bp,
                   const float* __restrict__ Wg1, const float* __restrict__ bg1,
                   float* __restrict__ hq)
{
    const int tid  = threadIdx.x;
    const int lane = tid & 63;
    const int wv   = tid >> 6;
    const int c    = lane >> 4;   // k-chunk group
    const int rl   = lane & 15;   // A-row within 16 / B-output col
    const int rowBase = blockIdx.x*64 + wv*16;

    const float* wrow = (rl < 8) ? (Wp + rl*256) : (Wg1 + (rl-8)*256);
    bf16x8 bfrag[8];
    #pragma unroll
    for (int kk=0; kk<8; ++kk){
        #pragma unroll
        for (int j=0; j<8; ++j) bfrag[kk][j] = bf16rnd(wrow[kk*32 + c*8 + j]);
    }
    const float aBias = (rl < 8) ? bp[rl] : bg1[rl-8];

    const float* xrow = x + (size_t)(rowBase + rl) * 256;
    f32x4 acc = {0.f, 0.f, 0.f, 0.f};
    #pragma unroll
    for (int kk=0; kk<8; ++kk){
        float4 v0 = *(const float4*)(xrow + kk*32 + c*8);
        float4 v1 = *(const float4*)(xrow + kk*32 + c*8 + 4);
        float xs[8] = {v0.x,v0.y,v0.z,v0.w, v1.x,v1.y,v1.z,v1.w};
        bf16x8 ahi, alo;
        #pragma unroll
        for (int j=0; j<8; ++j){
            unsigned u  = fbits(xs[j]);
            unsigned hb = (u + 0x8000u) & 0xFFFF0000u;   // rounded bf16 "hi"
            ahi[j] = (short)(hb >> 16);
            alo[j] = bf16rnd(xs[j] - bitsf(hb));         // residual -> bf16
        }
        acc = __builtin_amdgcn_mfma_f32_16x16x32_bf16(ahi, bfrag[kk], acc, 0, 0, 0);
        acc = __builtin_amdgcn_mfma_f32_16x16x32_bf16(alo, bfrag[kk], acc, 0, 0, 0);
    }
    // D layout: col = rl (output o), row = c*4 + r. Store: 16 lanes (rl=0..15) of
    // same (c,r) write one 64B-contiguous row segment.
    #pragma unroll
    for (int r=0; r<4; ++r){
        float v = acc[r] + aBias;
        if (rl >= 8) v = fmaxf(v, 0.f);                  // relu only on gate branch
        hq[(size_t)(rowBase + c*4 + r)*16 + rl] = v;
    }
}

// ======================= Kernel B: GRU rollout =======================
// 4 lanes per row (lane owns h-dims o and o+4); reads [row][16] h0/q from ws.
__global__ __launch_bounds__(256) __attribute__((amdgpu_waves_per_eu(4, 8)))
void phaseB_kernel(const float* __restrict__ hq, const float* __restrict__ last_step,
    const float* __restrict__ W_ih, const float* __restrict__ W_hh,
    const float* __restrict__ b_ih, const float* __restrict__ b_hh,
    const float* __restrict__ Wo,  const float* __restrict__ bo,
    const float* __restrict__ Wg2, const float* __restrict__ bg2,
    const float* __restrict__ log_decay, float* __restrict__ out)
{
    // r/z rows pre-scaled by log2e, n rows by 2*log2e (folds exp->exp2 into weights)
    __shared__ __attribute__((aligned(16))) float s_whh[24*8];
    __shared__ __attribute__((aligned(16))) float s_wih[24];
    __shared__ __attribute__((aligned(16))) float s_b1[16];   // (b_ih+b_hh)[0..15]*L2E
    __shared__ __attribute__((aligned(16))) float s_bin[8];   // b_ih[16..]*2L2E
    __shared__ __attribute__((aligned(16))) float s_bhn[8];   // b_hh[16..]*2L2E
    __shared__ __attribute__((aligned(16))) float s_wo[8];
    __shared__ __attribute__((aligned(16))) float s_gw[28*8]; // Wg2*L2E
    __shared__ __attribute__((aligned(16))) float s_gb[28];   // bg2*L2E

    const int tid = threadIdx.x;
    if (tid < 192) s_whh[tid] = W_hh[tid] * (tid < 128 ? L2E : 2.0f*L2E);
    if (tid < 224) s_gw[tid]  = Wg2[tid] * L2E;
    if (tid < 28)  s_gb[tid]  = bg2[tid] * L2E;
    if (tid < 24)  s_wih[tid] = W_ih[tid] * (tid < 16 ? L2E : 2.0f*L2E);
    if (tid < 16)  s_b1[tid]  = (b_ih[tid] + b_hh[tid]) * L2E;
    if (tid < 8){
        s_bin[tid] = b_ih[16+tid] * (2.0f*L2E);
        s_bhn[tid] = b_hh[16+tid] * (2.0f*L2E);
        s_wo[tid]  = Wo[tid];
    }
    __syncthreads();

    const int row  = tid >> 2;            // local row 0..63
    const int o    = tid & 3;
    const int rowG = blockIdx.x*64 + row;
    const int dd0 = o, dd1 = o^1, dd2 = o^2, dd3 = o^3;   // dim order after DPP allgather

    // h0 + q: 64B per row, quad-redundant reads absorbed by L1
    const float4* hv = (const float4*)(hq + (size_t)rowG * 16);
    float4 p0 = hv[0], p1 = hv[1], p2 = hv[2], p3 = hv[3];
    float hf[8] = {p0.x,p0.y,p0.z,p0.w, p1.x,p1.y,p1.z,p1.w};
    float qv[8] = {p2.x,p2.y,p2.z,p2.w, p3.x,p3.y,p3.z,p3.w};

    float hOwn0 = hf[dd0], hOwn1 = hf[4+dd0];
    h2 hh[4] = { PKH2(hf[dd0],hf[dd1]),     PKH2(hf[dd2],hf[dd3]),
                 PKH2(hf[4+dd0],hf[4+dd1]), PKH2(hf[4+dd2],hf[4+dd3]) };

    // per-lane W_hh rows (6) packed in dd-order: r:{o,o+4} z:{8+o,12+o} n:{16+o,20+o}
    const int rws[6] = { o, o+4, 8+o, 12+o, 16+o, 20+o };
    h2 wk[6][4];
    #pragma unroll
    for (int rr=0; rr<6; ++rr){
        const float* wp_ = &s_whh[rws[rr]*8];
        wk[rr][0] = PKH2(wp_[dd0], wp_[dd1]);     wk[rr][1] = PKH2(wp_[dd2], wp_[dd3]);
        wk[rr][2] = PKH2(wp_[4+dd0], wp_[4+dd1]); wk[rr][3] = PKH2(wp_[4+dd2], wp_[4+dd3]);
    }
    const float w_r0 = s_wih[o],    w_r1 = s_wih[o+4];
    const float w_z0 = s_wih[8+o],  w_z1 = s_wih[12+o];
    const float w_n0 = s_wih[16+o], w_n1 = s_wih[20+o];
    const float b_r0 = s_b1[o],   b_r1 = s_b1[o+4];
    const float b_z0 = s_b1[8+o], b_z1 = s_b1[12+o];
    const float b_in0 = s_bin[o], b_in1 = s_bin[o+4];
    const float b_hn0 = s_bhn[o], b_hn1 = s_bhn[o+4];
    h2 wo2[4] = { PKH2(s_wo[dd0], s_wo[dd1]),     PKH2(s_wo[dd2], s_wo[dd3]),
                  PKH2(s_wo[4+dd0], s_wo[4+dd1]), PKH2(s_wo[4+dd2], s_wo[4+dd3]) };

    // gates fully pre-loop: lane o handles t = 4i+o
    float gates[7];
    #pragma unroll
    for (int i=0; i<7; ++i){
        const int t = 4*i + o;
        const float* gw = &s_gw[t*8];
        float gl = s_gb[t];
        #pragma unroll
        for (int j=0; j<8; ++j) gl = fmaf(gw[j], qv[j], gl);
        gates[i] = RCP(1.f + EXP2(-gl));
    }

    const float ls0 = last_step[rowG];
    const float boS = bo[0];
    float cur = ls0;
    float preds[7];

    #pragma unroll
    for (int t=0; t<TT; ++t){
        float sr0 = fmaf(cur, w_r0, b_r0), sr1 = fmaf(cur, w_r1, b_r1);
        float sz0 = fmaf(cur, w_z0, b_z0), sz1 = fmaf(cur, w_z1, b_z1);
        float gn0 = b_hn0, gn1 = b_hn1;
        #pragma unroll
        for (int k=0; k<4; ++k){
            sr0 = FDOT2(hh[k], wk[0][k], sr0);
            sr1 = FDOT2(hh[k], wk[1][k], sr1);
            sz0 = FDOT2(hh[k], wk[2][k], sz0);
            sz1 = FDOT2(hh[k], wk[3][k], sz1);
            gn0 = FDOT2(hh[k], wk[4][k], gn0);
            gn1 = FDOT2(hh[k], wk[5][k], gn1);
        }
        float r0 = RCP(1.f + EXP2(-sr0)), r1 = RCP(1.f + EXP2(-sr1));
        float e0 = EXP2(fmaf(r0, gn0, fmaf(cur, w_n0, b_in0)));
        float e1 = EXP2(fmaf(r1, gn1, fmaf(cur, w_n1, b_in1)));
        float nn0 = fmaf(-2.f, RCP(e0 + 1.f), 1.f);   // tanh, correct saturation
        float nn1 = fmaf(-2.f, RCP(e1 + 1.f), 1.f);
        float z0 = RCP(1.f + EXP2(-sz0)), z1 = RCP(1.f + EXP2(-sz1));
        hOwn0 = fmaf(z0, hOwn0 - nn0, nn0);
        hOwn1 = fmaf(z1, hOwn1 - nn1, nn1);

        // allgather h_new across the quad (DPP, VALU-rate)
        float a0 = DPP_XOR1(hOwn0), a1 = DPP_XOR1(hOwn1);
        float u0 = DPP_XOR2(hOwn0), u1 = DPP_XOR2(a0);
        float u2 = DPP_XOR2(hOwn1), u3 = DPP_XOR2(a1);
        hh[0] = PKH2(hOwn0, a0); hh[1] = PKH2(u0, u1);
        hh[2] = PKH2(hOwn1, a1); hh[3] = PKH2(u2, u3);

        // pred = Wo.h_new + bo (all 4 lanes agree)
        float p = boS;
        #pragma unroll
        for (int k=0; k<4; ++k) p = FDOT2(hh[k], wo2[k], p);
        preds[t>>2] = ((t & 3) == o) ? p : preds[t>>2];   // keep own t's
        cur = p;
    }

    // ---- combine with decay + store (lane writes its 7 t's; quad covers 16B/chunk) ----
    const float lam = EXP2(log_decay[0] * L2E);           // exp(log_decay)
    const float c1  = -lam * L2E;                          // exp(-lam*T) = EXP2(c1*T)
    float* orow = out + (size_t)rowG * TT;
    #pragma unroll
    for (int i=0; i<7; ++i){
        const int t = 4*i + o;
        float dp = ls0 * EXP2(c1 * (float)(t+1));
        orow[t] = fmaf(gates[i], preds[i] - dp, dp);
    }
}

extern "C" void kernel_launch(void* const* d_in, const int* in_sizes, int n_in,
                              void* d_out, int out_size, void* d_ws, size_t ws_size,
                              hipStream_t stream)
{
    const float* x         = (const float*)d_in[0];
    const float* last_step = (const float*)d_in[1];
    const float* W_ih      = (const float*)d_in[2];
    const float* W_hh      = (const float*)d_in[3];
    const float* b_ih      = (const float*)d_in[4];
    const float* b_hh      = (const float*)d_in[5];
    const float* Wp        = (const float*)d_in[6];
    const float* bp        = (const float*)d_in[7];
    const float* Wo        = (const float*)d_in[8];
    const float* bo        = (const float*)d_in[9];
    const float* Wg1       = (const float*)d_in[10];
    const float* bg1       = (const float*)d_in[11];
    const float* Wg2       = (const float*)d_in[12];
    const float* bg2       = (const float*)d_in[13];
    const float* log_decay = (const float*)d_in[14];
    float* hq = (float*)d_ws;   // [131072][16] f32 = 8.4 MB

    hipLaunchKernelGGL(phaseA_kernel, dim3(2048), dim3(256), 0, stream,
                       x, Wp, bp, Wg1, bg1, hq);
    hipLaunchKernelGGL(phaseB_kernel, dim3(2048), dim3(256), 0, stream,
                       hq, last_step, W_ih, W_hh, b_ih, b_hh, Wo, bo,
                       Wg2, bg2, log_decay, (float*)d_out);
}

// Round 8
// 233.005 us; speedup vs baseline: 1.1281x; 1.1281x over previous
//
#include <hip/hip_runtime.h>

#define TT 28
#define L2E 1.4426950408889634f

typedef __attribute__((ext_vector_type(8))) short bf16x8;
typedef __attribute__((ext_vector_type(4))) float f32x4;
typedef __attribute__((ext_vector_type(4))) unsigned u32x4;
typedef _Float16 h2 __attribute__((ext_vector_type(2)));
typedef __fp16 fp16x2 __attribute__((ext_vector_type(2)));

__device__ __forceinline__ unsigned fbits(float f){ union{float f; unsigned u;} v; v.f=f; return v.u; }
__device__ __forceinline__ short bf16rnd(float f){ return (short)((fbits(f)+0x8000u)>>16); }

__device__ __forceinline__ h2 PKH2(float a, float b){
    fp16x2 t = __builtin_amdgcn_cvt_pkrtz(a, b);   // v_cvt_pkrtz_f16_f32
    return __builtin_bit_cast(h2, t);
}

#if __has_builtin(__builtin_amdgcn_fdot2)
#define FDOT2(a,b,c) __builtin_amdgcn_fdot2((a),(b),(c),false)
#else
__device__ __forceinline__ float FDOT2(h2 a, h2 b, float c){
    return fmaf((float)a.x,(float)b.x, fmaf((float)a.y,(float)b.y,(c)));
}
#endif
#if __has_builtin(__builtin_amdgcn_exp2f)
#define EXP2(x) __builtin_amdgcn_exp2f(x)
#else
#define EXP2(x) exp2f(x)
#endif
#if __has_builtin(__builtin_amdgcn_rcpf)
#define RCP(x) __builtin_amdgcn_rcpf(x)
#else
#define RCP(x) (1.f/(x))
#endif

// quad_perm DPP: xor1 = [1,0,3,2] = 0xB1, xor2 = [2,3,0,1] = 0x4E. Full-rate VALU, no LDS pipe.
#if __has_builtin(__builtin_amdgcn_mov_dpp)
#define DPP_XOR1(x) __builtin_bit_cast(float, __builtin_amdgcn_mov_dpp(__builtin_bit_cast(int,(float)(x)), 0xB1, 0xF, 0xF, true))
#define DPP_XOR2(x) __builtin_bit_cast(float, __builtin_amdgcn_mov_dpp(__builtin_bit_cast(int,(float)(x)), 0x4E, 0xF, 0xF, true))
#else
#define DPP_XOR1(x) __shfl_xor((x), 1, 64)
#define DPP_XOR2(x) __shfl_xor((x), 2, 64)
#endif

// 131072 rows. 2048 blocks x 256 threads; Phase A: 4 waves x 16 rows (MFMA, single
// rounded-bf16 pass); Phase B: 4 lanes per row (lane owns h-dims o and o+4).
__global__ __launch_bounds__(256) __attribute__((amdgpu_waves_per_eu(5, 8)))
void horizon_kernel(
    const float* __restrict__ x, const float* __restrict__ last_step,
    const float* __restrict__ W_ih, const float* __restrict__ W_hh,
    const float* __restrict__ b_ih, const float* __restrict__ b_hh,
    const float* __restrict__ Wp, const float* __restrict__ bp,
    const float* __restrict__ Wo, const float* __restrict__ bo,
    const float* __restrict__ Wg1, const float* __restrict__ bg1,
    const float* __restrict__ Wg2, const float* __restrict__ bg2,
    const float* __restrict__ log_decay, float* __restrict__ out)
{
    // r/z rows pre-scaled by log2e, n rows by 2*log2e (folds exp->exp2 into weights)
    __shared__ __attribute__((aligned(16))) float s_whh[24*8];
    __shared__ __attribute__((aligned(16))) float s_wih[24];
    __shared__ __attribute__((aligned(16))) float s_b1[16];   // (b_ih+b_hh)[0..15]*L2E
    __shared__ __attribute__((aligned(16))) float s_bin[8];   // b_ih[16..]*2L2E
    __shared__ __attribute__((aligned(16))) float s_bhn[8];   // b_hh[16..]*2L2E
    __shared__ __attribute__((aligned(16))) float s_wo[8];
    __shared__ __attribute__((aligned(16))) float s_gw[28*8]; // Wg2*L2E
    __shared__ __attribute__((aligned(16))) float s_gb[28];   // bg2*L2E
    __shared__ __attribute__((aligned(16))) float s_park[64][17]; // [row][0..7]=h0, [8..15]=q

    const int tid = threadIdx.x;

    if (tid < 192) s_whh[tid] = W_hh[tid] * (tid < 128 ? L2E : 2.0f*L2E);
    if (tid < 224) s_gw[tid]  = Wg2[tid] * L2E;
    if (tid < 28)  s_gb[tid]  = bg2[tid] * L2E;
    if (tid < 24)  s_wih[tid] = W_ih[tid] * (tid < 16 ? L2E : 2.0f*L2E);
    if (tid < 16)  s_b1[tid]  = (b_ih[tid] + b_hh[tid]) * L2E;
    if (tid < 8){
        s_bin[tid] = b_ih[16+tid] * (2.0f*L2E);
        s_bhn[tid] = b_hh[16+tid] * (2.0f*L2E);
        s_wo[tid]  = Wo[tid];
    }
    __syncthreads();   // only barrier: staging -> everything below is per-wave/per-lane

    const int lane = tid & 63;
    const int wv   = tid >> 6;
    const int c    = lane >> 4;   // k-chunk group
    const int rl   = lane & 15;   // A-row within 16 / B-output col
    const int rowBase = blockIdx.x * 64;

    // ---- Phase A: wave wv computes rows rowBase+wv*16..+15, outputs h0(Wp)+q(Wg1) ----
    {
        const float* wrow = (rl < 8) ? (Wp + rl*256) : (Wg1 + (rl-8)*256);
        bf16x8 bfrag[8];
        #pragma unroll
        for (int kk=0; kk<8; ++kk){
            #pragma unroll
            for (int j=0; j<8; ++j) bfrag[kk][j] = bf16rnd(wrow[kk*32 + c*8 + j]);
        }
        const float aBias = (rl < 8) ? bp[rl] : bg1[rl-8];
        const float* xrow = x + (size_t)(rowBase + wv*16 + rl) * 256;
        f32x4 acc = {0.f, 0.f, 0.f, 0.f};
        #pragma unroll
        for (int kk=0; kk<8; ++kk){
            float4 v0 = *(const float4*)(xrow + kk*32 + c*8);
            float4 v1 = *(const float4*)(xrow + kk*32 + c*8 + 4);
            float xs[8] = {v0.x,v0.y,v0.z,v0.w, v1.x,v1.y,v1.z,v1.w};
            // round-half-up bf16 pairs packed with one v_perm each: 3 inst / 2 elems
            u32x4 aw;
            #pragma unroll
            for (int j=0; j<4; ++j){
                unsigned ta = fbits(xs[2*j])   + 0x8000u;
                unsigned tb = fbits(xs[2*j+1]) + 0x8000u;
                aw[j] = __builtin_amdgcn_perm(tb, ta, 0x07060302u); // [ta.b2,ta.b3,tb.b2,tb.b3]
            }
            bf16x8 ahi = __builtin_bit_cast(bf16x8, aw);
            acc = __builtin_amdgcn_mfma_f32_16x16x32_bf16(ahi, bfrag[kk], acc, 0, 0, 0);
        }
        // D layout: col = lane&15 (output o), row = c*4 + r
        #pragma unroll
        for (int r=0; r<4; ++r){
            float v = acc[r] + aBias;
            if (rl >= 8) v = fmaxf(v, 0.f);
            s_park[wv*16 + c*4 + r][rl] = v;
        }
    }
    // Phase B below reads only rows this same wave wrote -> per-wave LDS ordering suffices.

    // ---- Phase B: 4 lanes per row; lane owns dims o and o+4 ----
    const int row = tid >> 2;     // local row 0..63 (wave w handles rows 16w..16w+15)
    const int o   = tid & 3;
    const int rowG = rowBase + row;
    const int dd0 = o, dd1 = o^1, dd2 = o^2, dd3 = o^3;   // dim order after DPP allgather

    float hf[8], qv[8];
    #pragma unroll
    for (int j=0; j<8; ++j){ hf[j] = s_park[row][j]; qv[j] = s_park[row][8+j]; }

    float hOwn0 = hf[dd0], hOwn1 = hf[4+dd0];
    h2 hh[4] = { PKH2(hf[dd0],hf[dd1]),     PKH2(hf[dd2],hf[dd3]),
                 PKH2(hf[4+dd0],hf[4+dd1]), PKH2(hf[4+dd2],hf[4+dd3]) };

    // per-lane W_hh rows (6) packed in dd-order: r:{o,o+4} z:{8+o,12+o} n:{16+o,20+o}
    const int rws[6] = { o, o+4, 8+o, 12+o, 16+o, 20+o };
    h2 wk[6][4];
    #pragma unroll
    for (int rr=0; rr<6; ++rr){
        const float* wp_ = &s_whh[rws[rr]*8];
        wk[rr][0] = PKH2(wp_[dd0], wp_[dd1]);     wk[rr][1] = PKH2(wp_[dd2], wp_[dd3]);
        wk[rr][2] = PKH2(wp_[4+dd0], wp_[4+dd1]); wk[rr][3] = PKH2(wp_[4+dd2], wp_[4+dd3]);
    }
    const float w_r0 = s_wih[o],    w_r1 = s_wih[o+4];
    const float w_z0 = s_wih[8+o],  w_z1 = s_wih[12+o];
    const float w_n0 = s_wih[16+o], w_n1 = s_wih[20+o];
    const float b_r0 = s_b1[o],   b_r1 = s_b1[o+4];
    const float b_z0 = s_b1[8+o], b_z1 = s_b1[12+o];
    const float b_in0 = s_bin[o], b_in1 = s_bin[o+4];
    const float b_hn0 = s_bhn[o], b_hn1 = s_bhn[o+4];
    h2 wo2[4] = { PKH2(s_wo[dd0], s_wo[dd1]),     PKH2(s_wo[dd2], s_wo[dd3]),
                  PKH2(s_wo[4+dd0], s_wo[4+dd1]), PKH2(s_wo[4+dd2], s_wo[4+dd3]) };

    // gates fully pre-loop: lane o handles t = 4i+o
    float gates[7];
    #pragma unroll
    for (int i=0; i<7; ++i){
        const int t = 4*i + o;
        const float* gw = &s_gw[t*8];
        float gl = s_gb[t];
        #pragma unroll
        for (int j=0; j<8; ++j) gl = fmaf(gw[j], qv[j], gl);
        gates[i] = RCP(1.f + EXP2(-gl));
    }

    const float ls0 = last_step[rowG];
    const float boS = bo[0];
    float cur = ls0;
    float preds[7];

    #pragma unroll
    for (int t=0; t<TT; ++t){
        float sr0 = fmaf(cur, w_r0, b_r0), sr1 = fmaf(cur, w_r1, b_r1);
        float sz0 = fmaf(cur, w_z0, b_z0), sz1 = fmaf(cur, w_z1, b_z1);
        float gn0 = b_hn0, gn1 = b_hn1;
        #pragma unroll
        for (int k=0; k<4; ++k){
            sr0 = FDOT2(hh[k], wk[0][k], sr0);
            sr1 = FDOT2(hh[k], wk[1][k], sr1);
            sz0 = FDOT2(hh[k], wk[2][k], sz0);
            sz1 = FDOT2(hh[k], wk[3][k], sz1);
            gn0 = FDOT2(hh[k], wk[4][k], gn0);
            gn1 = FDOT2(hh[k], wk[5][k], gn1);
        }
        float r0 = RCP(1.f + EXP2(-sr0)), r1 = RCP(1.f + EXP2(-sr1));
        float e0 = EXP2(fmaf(r0, gn0, fmaf(cur, w_n0, b_in0)));
        float e1 = EXP2(fmaf(r1, gn1, fmaf(cur, w_n1, b_in1)));
        float nn0 = fmaf(-2.f, RCP(e0 + 1.f), 1.f);   // tanh, correct saturation
        float nn1 = fmaf(-2.f, RCP(e1 + 1.f), 1.f);
        float z0 = RCP(1.f + EXP2(-sz0)), z1 = RCP(1.f + EXP2(-sz1));
        hOwn0 = fmaf(z0, hOwn0 - nn0, nn0);
        hOwn1 = fmaf(z1, hOwn1 - nn1, nn1);

        // allgather h_new across the quad (DPP, VALU-rate)
        float a0 = DPP_XOR1(hOwn0), a1 = DPP_XOR1(hOwn1);
        float u0 = DPP_XOR2(hOwn0), u1 = DPP_XOR2(a0);
        float u2 = DPP_XOR2(hOwn1), u3 = DPP_XOR2(a1);
        hh[0] = PKH2(hOwn0, a0); hh[1] = PKH2(u0, u1);
        hh[2] = PKH2(hOwn1, a1); hh[3] = PKH2(u2, u3);

        // pred = Wo.h_new + bo (all 4 lanes agree)
        float p = boS;
        #pragma unroll
        for (int k=0; k<4; ++k) p = FDOT2(hh[k], wo2[k], p);
        preds[t>>2] = ((t & 3) == o) ? p : preds[t>>2];   // keep own t's
        cur = p;
    }

    // ---- combine with decay + store (lane writes its 7 t's; quad covers 16B/chunk) ----
    const float lam = EXP2(log_decay[0] * L2E);           // exp(log_decay)
    const float c1  = -lam * L2E;                          // exp(-lam*T) = EXP2(c1*T)
    float* orow = out + (size_t)rowG * TT;
    #pragma unroll
    for (int i=0; i<7; ++i){
        const int t = 4*i + o;
        float dp = ls0 * EXP2(c1 * (float)(t+1));
        orow[t] = fmaf(gates[i], preds[i] - dp, dp);
    }
}

extern "C" void kernel_launch(void* const* d_in, const int* in_sizes, int n_in,
                              void* d_out, int out_size, void* d_ws, size_t ws_size,
                              hipStream_t stream)
{
    const float* x         = (const float*)d_in[0];
    const float* last_step = (const float*)d_in[1];
    const float* W_ih      = (const float*)d_in[2];
    const float* W_hh      = (const float*)d_in[3];
    const float* b_ih      = (const float*)d_in[4];
    const float* b_hh      = (const float*)d_in[5];
    const float* Wp        = (const float*)d_in[6];
    const float* bp        = (const float*)d_in[7];
    const float* Wo        = (const float*)d_in[8];
    const float* bo        = (const float*)d_in[9];
    const float* Wg1       = (const float*)d_in[10];
    const float* bg1       = (const float*)d_in[11];
    const float* Wg2       = (const float*)d_in[12];
    const float* bg2       = (const float*)d_in[13];
    const float* log_decay = (const float*)d_in[14];

    hipLaunchKernelGGL(horizon_kernel, dim3(2048), dim3(256), 0, stream,
                       x, last_step, W_ih, W_hh, b_ih, b_hh, Wp, bp, Wo, bo,
                       Wg1, bg1, Wg2, bg2, log_decay, (float*)d_out);
}